// Round 2
// baseline (1302.605 us; speedup 1.0000x reference)
//
#include <hip/hip_runtime.h>
#include <math.h>

#define D_MODEL 1024
#define NHEADS  16
#define DK      64
#define SEQ     2048
#define BATCH   2
#define MROWS   (BATCH*SEQ)   // 4096

// ---------------------------------------------------------------------------
// GEMM: C[M,N] = A[M,K] @ W[N,K]^T + bias[N]   (torch Linear layout)
// 64x64 block tile, 256 threads, 4x4 microtile per thread, K-tile = 16.
// (unchanged from round 1 — ~65 TF fp32; MFMA conversion is next round)
// ---------------------------------------------------------------------------
__global__ __launch_bounds__(256) void gemm_xwt(
    const float* __restrict__ A, const float* __restrict__ W,
    const float* __restrict__ bias, float* __restrict__ C,
    int M, int N, int K)
{
    __shared__ float As[16][68];   // [k][m]
    __shared__ float Ws[16][68];   // [k][n]
    const int tid = threadIdx.x;
    const int tx = tid & 15, ty = tid >> 4;
    const int bm = blockIdx.x * 64;
    const int bn = blockIdx.y * 64;

    float acc[4][4] = {};

    for (int k0 = 0; k0 < K; k0 += 16) {
        __syncthreads();
#pragma unroll
        for (int l = 0; l < 4; ++l) {
            int idx = tid + l * 256;        // 0..1023
            int k = idx & 15;
            int m = idx >> 4;
            As[k][m] = A[(size_t)(bm + m) * K + k0 + k];
            Ws[k][m] = W[(size_t)(bn + m) * K + k0 + k];
        }
        __syncthreads();
#pragma unroll
        for (int k = 0; k < 16; ++k) {
            float4 av = *(const float4*)&As[k][ty * 4];
            float4 wv = *(const float4*)&Ws[k][tx * 4];
            float a[4] = {av.x, av.y, av.z, av.w};
            float w[4] = {wv.x, wv.y, wv.z, wv.w};
#pragma unroll
            for (int i = 0; i < 4; ++i)
#pragma unroll
                for (int j = 0; j < 4; ++j)
                    acc[i][j] = fmaf(a[i], w[j], acc[i][j]);
        }
    }

#pragma unroll
    for (int i = 0; i < 4; ++i) {
        int m = bm + ty * 4 + i;
#pragma unroll
        for (int j = 0; j < 4; ++j) {
            int n = bn + tx * 4 + j;
            C[(size_t)m * N + n] = acc[i][j] + bias[n];
        }
    }
}

// ---------------------------------------------------------------------------
// Causal flash attention, fp32, rewritten:
//  - register-resident online softmax (shfl_xor over the 16-lane row group)
//  - row-major LDS tiles, XOR-swizzled float4 groups -> conflict-minimal b128
//  - exp2-domain softmax, scale folded into Q at staging
//  - big q-tiles dispatched first (causal tail balance)
// Grid: (SEQ/64 q-tiles, BATCH*NHEADS), 256 threads.
// ---------------------------------------------------------------------------

// swizzled float4 accessor: row r (0..63), float4-group g (0..15), stride 64
__device__ __forceinline__ float4* sw4(float* base, int r, int g) {
    return (float4*)(base + r * 64 + ((g ^ (r & 15)) << 2));
}

__global__ __launch_bounds__(256) void flash_attn(
    const float* __restrict__ Qp, const float* __restrict__ Kp,
    const float* __restrict__ Vp, float* __restrict__ Hc)
{
    const int qt = gridDim.x - 1 - blockIdx.x;   // big tiles first
    const int bh = blockIdx.y;
    const int b = bh >> 4, h = bh & 15;
    const int tid = threadIdx.x;
    const int tx = tid & 15, ty = tid >> 4;      // tx: col group, ty: row group

    __shared__ float Qs[64 * 64];
    __shared__ float Ks[64 * 64];
    __shared__ float Vs[64 * 64];
    __shared__ float Ss[64 * 64];

    const size_t base = (size_t)(b * SEQ) * D_MODEL + h * DK;
    const float qscale = 0.125f * 1.44269504088896340736f;  // 1/sqrt(64)*log2(e)

    // stage Q tile (row-major, swizzled, pre-scaled)
#pragma unroll
    for (int l = 0; l < 4; ++l) {
        int idx = tid + l * 256;         // 0..1023
        int r = idx >> 4, g = idx & 15;
        float4 q = *(const float4*)&Qp[base + (size_t)(qt * 64 + r) * D_MODEL + g * 4];
        q.x *= qscale; q.y *= qscale; q.z *= qscale; q.w *= qscale;
        *sw4(Qs, r, g) = q;
    }

    float o[4][4] = {};
    float mrow[4] = {-INFINITY, -INFINITY, -INFINITY, -INFINITY};
    float lrow[4] = {0.f, 0.f, 0.f, 0.f};

    for (int kt = 0; kt <= qt; ++kt) {
        __syncthreads();
        // stage K,V tiles
#pragma unroll
        for (int l = 0; l < 4; ++l) {
            int idx = tid + l * 256;
            int r = idx >> 4, g = idx & 15;
            size_t gaddr = base + (size_t)(kt * 64 + r) * D_MODEL + g * 4;
            *sw4(Ks, r, g) = *(const float4*)&Kp[gaddr];
            *sw4(Vs, r, g) = *(const float4*)&Vp[gaddr];
        }
        __syncthreads();

        // S = (Q/sqrt(dk)*log2e) K^T : per-thread 4x4 dot-product fragment
        float s[4][4] = {};
#pragma unroll 4
        for (int g = 0; g < 16; ++g) {
            float4 qv[4], kv[4];
#pragma unroll
            for (int i = 0; i < 4; ++i) qv[i] = *sw4(Qs, ty * 4 + i, g);
#pragma unroll
            for (int j = 0; j < 4; ++j) kv[j] = *sw4(Ks, tx * 4 + j, g);
#pragma unroll
            for (int i = 0; i < 4; ++i)
#pragma unroll
                for (int j = 0; j < 4; ++j) {
                    s[i][j] = fmaf(qv[i].x, kv[j].x, s[i][j]);
                    s[i][j] = fmaf(qv[i].y, kv[j].y, s[i][j]);
                    s[i][j] = fmaf(qv[i].z, kv[j].z, s[i][j]);
                    s[i][j] = fmaf(qv[i].w, kv[j].w, s[i][j]);
                }
        }

        // causal mask on the diagonal tile (log2 domain -> -inf)
        if (kt == qt) {
#pragma unroll
            for (int i = 0; i < 4; ++i) {
                int r = ty * 4 + i;
#pragma unroll
                for (int j = 0; j < 4; ++j)
                    if (tx * 4 + j > r) s[i][j] = -INFINITY;
            }
        }

        // online softmax, fully in registers
#pragma unroll
        for (int i = 0; i < 4; ++i) {
            float tm = fmaxf(fmaxf(s[i][0], s[i][1]), fmaxf(s[i][2], s[i][3]));
#pragma unroll
            for (int off = 1; off < 16; off <<= 1)
                tm = fmaxf(tm, __shfl_xor(tm, off, 64));
            float mnew = fmaxf(mrow[i], tm);
            float alpha = exp2f(mrow[i] - mnew);   // 0 when mrow == -inf
            float rs = 0.f;
#pragma unroll
            for (int j = 0; j < 4; ++j) {
                float p = exp2f(s[i][j] - mnew);
                s[i][j] = p;
                rs += p;
            }
#pragma unroll
            for (int off = 1; off < 16; off <<= 1)
                rs += __shfl_xor(rs, off, 64);
            lrow[i] = lrow[i] * alpha + rs;
            mrow[i] = mnew;
#pragma unroll
            for (int j = 0; j < 4; ++j) o[i][j] *= alpha;
        }

        // write P fragment to LDS (swizzled float4)
#pragma unroll
        for (int i = 0; i < 4; ++i)
            *sw4(Ss, ty * 4 + i, tx) = make_float4(s[i][0], s[i][1], s[i][2], s[i][3]);
        __syncthreads();

        // O += P @ V
#pragma unroll 4
        for (int g = 0; g < 16; ++g) {
            float4 pr4[4];
#pragma unroll
            for (int i = 0; i < 4; ++i) pr4[i] = *sw4(Ss, ty * 4 + i, g);
            const float* pr = (const float*)pr4;
#pragma unroll
            for (int kk = 0; kk < 4; ++kk) {
                float4 vb = *sw4(Vs, g * 4 + kk, tx);
#pragma unroll
                for (int i = 0; i < 4; ++i) {
                    float p = pr[i * 4 + kk];
                    o[i][0] = fmaf(p, vb.x, o[i][0]);
                    o[i][1] = fmaf(p, vb.y, o[i][1]);
                    o[i][2] = fmaf(p, vb.z, o[i][2]);
                    o[i][3] = fmaf(p, vb.w, o[i][3]);
                }
            }
        }
    }

    // epilogue: divide by l, write Hcat [B,S,D]
#pragma unroll
    for (int i = 0; i < 4; ++i) {
        int r = ty * 4 + i;
        float invl = 1.f / lrow[i];
        float4 w = make_float4(o[i][0] * invl, o[i][1] * invl,
                               o[i][2] * invl, o[i][3] * invl);
        *(float4*)&Hc[base + (size_t)(qt * 64 + r) * D_MODEL + tx * 4] = w;
    }
}

extern "C" void kernel_launch(void* const* d_in, const int* in_sizes, int n_in,
                              void* d_out, int out_size, void* d_ws, size_t ws_size,
                              hipStream_t stream) {
    const float* inQ = (const float*)d_in[0];
    const float* inK = (const float*)d_in[1];
    const float* inV = (const float*)d_in[2];
    const float* Wq  = (const float*)d_in[3];
    const float* bq  = (const float*)d_in[4];
    const float* Wk  = (const float*)d_in[5];
    const float* bk  = (const float*)d_in[6];
    const float* Wv  = (const float*)d_in[7];
    const float* bv  = (const float*)d_in[8];
    const float* Wo  = (const float*)d_in[9];
    const float* bo  = (const float*)d_in[10];
    float* out = (float*)d_out;

    float* ws = (float*)d_ws;
    const size_t MK = (size_t)MROWS * D_MODEL;   // 4M floats = 16 MB
    float* Qp = ws;
    float* Kp = ws + MK;
    float* Vp = ws + 2 * MK;
    float* Hc = ws + 3 * MK;

    dim3 gg(MROWS / 64, D_MODEL / 64);
    gemm_xwt<<<gg, 256, 0, stream>>>(inQ, Wq, bq, Qp, MROWS, D_MODEL, D_MODEL);
    gemm_xwt<<<gg, 256, 0, stream>>>(inK, Wk, bk, Kp, MROWS, D_MODEL, D_MODEL);
    gemm_xwt<<<gg, 256, 0, stream>>>(inV, Wv, bv, Vp, MROWS, D_MODEL, D_MODEL);

    dim3 ga(SEQ / 64, BATCH * NHEADS);
    flash_attn<<<ga, 256, 0, stream>>>(Qp, Kp, Vp, Hc);

    gemm_xwt<<<gg, 256, 0, stream>>>(Hc, Wo, bo, out, MROWS, D_MODEL, D_MODEL);
}

// Round 3
// 293.994 us; speedup vs baseline: 4.4307x; 4.4307x over previous
//
#include <hip/hip_runtime.h>
#include <math.h>

#define D_MODEL 1024
#define NHEADS  16
#define DK      64
#define SEQ     2048
#define BATCH   2
#define MROWS   4096   // BATCH*SEQ

typedef unsigned short ushort_t;
using short8 = __attribute__((ext_vector_type(8))) short;
using f32x4  = __attribute__((ext_vector_type(4))) float;

__device__ __forceinline__ ushort_t f2bf(float x) {
    unsigned u = __float_as_uint(x);
    u = (u + 0x7FFFu + ((u >> 16) & 1u)) >> 16;   // RNE
    return (ushort_t)u;
}

// async global->LDS, 16B per lane; LDS dest = wave-uniform base + lane*16
__device__ __forceinline__ void gll16(const ushort_t* g, ushort_t* l) {
    __builtin_amdgcn_global_load_lds(
        (const __attribute__((address_space(1))) void*)(g),
        (__attribute__((address_space(3))) void*)(l), 16, 0, 0);
}

// ---------------------------------------------------------------------------
// fp32 -> bf16 conversion, up to 4 tensors per launch (blockIdx.y selects)
// ---------------------------------------------------------------------------
__global__ __launch_bounds__(256) void cvt_bf16(
    const float* s0, const float* s1, const float* s2, const float* s3,
    ushort_t* d0, ushort_t* d1, ushort_t* d2, ushort_t* d3, int n)
{
    const float* s; ushort_t* d;
    switch (blockIdx.y) {
        case 0: s = s0; d = d0; break;
        case 1: s = s1; d = d1; break;
        case 2: s = s2; d = d2; break;
        default: s = s3; d = d3; break;
    }
    int i = (blockIdx.x * 256 + threadIdx.x) * 4;
    if (i < n) {
        float4 v = *(const float4*)&s[i];
        ushort4 o;
        o.x = f2bf(v.x); o.y = f2bf(v.y); o.z = f2bf(v.z); o.w = f2bf(v.w);
        *(ushort4*)&d[i] = o;
    }
}

// ---------------------------------------------------------------------------
// bf16 MFMA GEMM:  C[M,N] = A[M,K] @ W[N,K]^T + bias
// 128x128 tile, BK=64, 256 threads (4 waves, each 64x64), global_load_lds.
// LDS layout: row-major, 8 groups of 8 bf16 per row, group XOR-swizzled by
// (row&7) -> frag reads are 2-way max (free). mode: 0=bf16 row-major out,
// 1=bf16 transposed out [B*H][DK][SEQ], 2=fp32 row-major out.
// ---------------------------------------------------------------------------
struct GemmArgs { const ushort_t* A; const ushort_t* W; const float* bias; void* C; int mode; };

__global__ __launch_bounds__(256) void gemm_mfma(GemmArgs g0, GemmArgs g1, GemmArgs g2)
{
    GemmArgs ga = (blockIdx.z == 0) ? g0 : ((blockIdx.z == 1) ? g1 : g2);
    __shared__ ushort_t As[128 * 64];
    __shared__ ushort_t Bs[128 * 64];

    const int tid  = threadIdx.x;
    const int w    = tid >> 6, lane = tid & 63;
    const int quad = lane >> 4, lx = lane & 15;
    const int mw = (w >> 1) * 64, nw = (w & 1) * 64;
    const int bm = blockIdx.x * 128, bn = blockIdx.y * 128;
    const int K = D_MODEL;

    f32x4 acc[4][4];
#pragma unroll
    for (int mt = 0; mt < 4; ++mt)
#pragma unroll
        for (int nt = 0; nt < 4; ++nt)
            acc[mt][nt] = (f32x4){0.f, 0.f, 0.f, 0.f};

    float bfr[4];
#pragma unroll
    for (int nt = 0; nt < 4; ++nt)
        bfr[nt] = ga.bias[bn + nw + nt * 16 + lx];

    for (int k0 = 0; k0 < K; k0 += 64) {
        __syncthreads();
#pragma unroll
        for (int i = 0; i < 4; ++i) {
            int r0 = (w * 4 + i) * 8;
            int rl = r0 + (lane >> 3);
            int g  = (lane & 7) ^ (rl & 7);
            gll16(&ga.A[(size_t)(bm + rl) * K + k0 + g * 8], &As[r0 * 64]);
            gll16(&ga.W[(size_t)(bn + rl) * K + k0 + g * 8], &Bs[r0 * 64]);
        }
        __syncthreads();

#pragma unroll
        for (int ks = 0; ks < 2; ++ks) {
            short8 af[4], bf[4];
#pragma unroll
            for (int mt = 0; mt < 4; ++mt) {
                int r = mw + mt * 16 + lx;
                af[mt] = *(const short8*)&As[r * 64 + (((ks * 4 + quad) ^ (r & 7)) << 3)];
            }
#pragma unroll
            for (int nt = 0; nt < 4; ++nt) {
                int r = nw + nt * 16 + lx;
                bf[nt] = *(const short8*)&Bs[r * 64 + (((ks * 4 + quad) ^ (r & 7)) << 3)];
            }
#pragma unroll
            for (int mt = 0; mt < 4; ++mt)
#pragma unroll
                for (int nt = 0; nt < 4; ++nt)
                    acc[mt][nt] = __builtin_amdgcn_mfma_f32_16x16x32_bf16(
                        af[mt], bf[nt], acc[mt][nt], 0, 0, 0);
        }
    }

    // epilogue: C-layout col=lane&15, row=quad*4+reg
    if (ga.mode == 0) {
        ushort_t* C = (ushort_t*)ga.C;
#pragma unroll
        for (int mt = 0; mt < 4; ++mt)
#pragma unroll
            for (int nt = 0; nt < 4; ++nt) {
                int n = bn + nw + nt * 16 + lx;
#pragma unroll
                for (int r = 0; r < 4; ++r) {
                    int m = bm + mw + mt * 16 + quad * 4 + r;
                    C[(size_t)m * D_MODEL + n] = f2bf(acc[mt][nt][r] + bfr[nt]);
                }
            }
    } else if (ga.mode == 2) {
        float* C = (float*)ga.C;
#pragma unroll
        for (int mt = 0; mt < 4; ++mt)
#pragma unroll
            for (int nt = 0; nt < 4; ++nt) {
                int n = bn + nw + nt * 16 + lx;
#pragma unroll
                for (int r = 0; r < 4; ++r) {
                    int m = bm + mw + mt * 16 + quad * 4 + r;
                    C[(size_t)m * D_MODEL + n] = acc[mt][nt][r] + bfr[nt];
                }
            }
    } else {
        // V^T output: Vt[(b*NHEADS+h)][d][s], 4 consecutive s per lane packed
        ushort_t* C = (ushort_t*)ga.C;
#pragma unroll
        for (int mt = 0; mt < 4; ++mt)
#pragma unroll
            for (int nt = 0; nt < 4; ++nt) {
                int n = bn + nw + nt * 16 + lx;
                int d = n & 63, h = n >> 6;
                int m0 = bm + mw + mt * 16 + quad * 4;
                int b = m0 >> 11, s0 = m0 & 2047;
                ushort4 pk;
                pk.x = f2bf(acc[mt][nt][0] + bfr[nt]);
                pk.y = f2bf(acc[mt][nt][1] + bfr[nt]);
                pk.z = f2bf(acc[mt][nt][2] + bfr[nt]);
                pk.w = f2bf(acc[mt][nt][3] + bfr[nt]);
                *(ushort4*)&C[((size_t)(b * NHEADS + h) * DK + d) * SEQ + s0] = pk;
            }
    }
}

// ---------------------------------------------------------------------------
// bf16 MFMA causal flash attention.
// Grid (SEQ/64, BATCH*NHEADS), 256 threads = 4 waves, each wave 16 q-rows.
// Q frags in registers; K & V^T tiles staged via global_load_lds (swizzled);
// P round-trips through per-wave padded LDS (C-layout -> A-layout).
// ---------------------------------------------------------------------------
__global__ __launch_bounds__(256) void flash_mfma(
    const ushort_t* __restrict__ Qp, const ushort_t* __restrict__ Kp,
    const ushort_t* __restrict__ Vt, ushort_t* __restrict__ Hc)
{
    const int qt = (int)gridDim.x - 1 - (int)blockIdx.x;   // big tiles first
    const int bh = blockIdx.y;
    const int b = bh >> 4, h = bh & 15;
    const int tid  = threadIdx.x;
    const int w    = tid >> 6, lane = tid & 63;
    const int quad = lane >> 4, lx = lane & 15;

    __shared__ ushort_t Ks[64 * 64];
    __shared__ ushort_t Vs[64 * 64];      // V^T tile: row d, col k
    __shared__ ushort_t Ps[4][16 * 72];   // per-wave P, padded to 72 (16B-aligned rows)

    const size_t qbase = (size_t)(b * SEQ) * D_MODEL + h * DK;
    const size_t vbase = (size_t)bh * DK * SEQ;

    // Q fragments (rows qt*64 + w*16 + lx), resident across all k-tiles
    short8 qf[2];
    {
        size_t ro = qbase + (size_t)(qt * 64 + w * 16 + lx) * D_MODEL + quad * 8;
        qf[0] = *(const short8*)&Qp[ro];
        qf[1] = *(const short8*)&Qp[ro + 32];
    }

    f32x4 O[4];
#pragma unroll
    for (int nt = 0; nt < 4; ++nt) O[nt] = (f32x4){0.f, 0.f, 0.f, 0.f};
    float mrow[4] = {-INFINITY, -INFINITY, -INFINITY, -INFINITY};
    float lrow[4] = {0.f, 0.f, 0.f, 0.f};
    const float sc = 0.125f * 1.44269504088896340736f;   // 1/sqrt(dk) * log2(e)
    const int rowl = w * 16 + quad * 4;

    for (int kt = 0; kt <= qt; ++kt) {
        __syncthreads();
#pragma unroll
        for (int i = 0; i < 2; ++i) {
            int r0 = (w + i * 4) * 8;
            int rl = r0 + (lane >> 3);
            int g  = (lane & 7) ^ (rl & 7);
            gll16(&Kp[qbase + (size_t)(kt * 64 + rl) * D_MODEL + g * 8], &Ks[r0 * 64]);
            gll16(&Vt[vbase + (size_t)rl * SEQ + kt * 64 + g * 8], &Vs[r0 * 64]);
        }
        __syncthreads();

        // S = Q K^T (fp32 accum)
        f32x4 s[4];
#pragma unroll
        for (int nt = 0; nt < 4; ++nt) {
            int r = nt * 16 + lx;
            short8 kf0 = *(const short8*)&Ks[r * 64 + ((quad ^ (r & 7)) << 3)];
            short8 kf1 = *(const short8*)&Ks[r * 64 + (((4 + quad) ^ (r & 7)) << 3)];
            f32x4 z = (f32x4){0.f, 0.f, 0.f, 0.f};
            z = __builtin_amdgcn_mfma_f32_16x16x32_bf16(qf[0], kf0, z, 0, 0, 0);
            z = __builtin_amdgcn_mfma_f32_16x16x32_bf16(qf[1], kf1, z, 0, 0, 0);
            s[nt] = z;
        }

        // scale (+ causal mask on diagonal tile), exp2 domain
#pragma unroll
        for (int nt = 0; nt < 4; ++nt)
#pragma unroll
            for (int r = 0; r < 4; ++r) {
                float v = s[nt][r] * sc;
                if (kt == qt && (nt * 16 + lx) > (rowl + r)) v = -INFINITY;
                s[nt][r] = v;
            }

        // online softmax, per row r (rows quad*4+r, cols = 16-lane group)
#pragma unroll
        for (int r = 0; r < 4; ++r) {
            float tm = fmaxf(fmaxf(s[0][r], s[1][r]), fmaxf(s[2][r], s[3][r]));
#pragma unroll
            for (int off = 1; off < 16; off <<= 1)
                tm = fmaxf(tm, __shfl_xor(tm, off, 64));
            float mnew = fmaxf(mrow[r], tm);
            float alpha = __builtin_amdgcn_exp2f(mrow[r] - mnew);
            mrow[r] = mnew;
            float rs = 0.f;
#pragma unroll
            for (int nt = 0; nt < 4; ++nt) {
                float p = __builtin_amdgcn_exp2f(s[nt][r] - mnew);
                s[nt][r] = p;
                rs += p;
            }
#pragma unroll
            for (int off = 1; off < 16; off <<= 1)
                rs += __shfl_xor(rs, off, 64);
            lrow[r] = lrow[r] * alpha + rs;
#pragma unroll
            for (int nt = 0; nt < 4; ++nt) O[nt][r] *= alpha;
        }

        // P: C-layout regs -> bf16 LDS (per-wave, no barrier needed)
#pragma unroll
        for (int nt = 0; nt < 4; ++nt)
#pragma unroll
            for (int r = 0; r < 4; ++r)
                Ps[w][(quad * 4 + r) * 72 + nt * 16 + lx] = f2bf(s[nt][r]);

        // P A-frags (same-wave LDS RAW: DS ops are in-order per wave)
        short8 pf0 = *(const short8*)&Ps[w][lx * 72 + quad * 8];
        short8 pf1 = *(const short8*)&Ps[w][lx * 72 + 32 + quad * 8];

        // O += P @ V  (B-operand = V^T rows = d)
#pragma unroll
        for (int nt = 0; nt < 4; ++nt) {
            int r = nt * 16 + lx;
            short8 vf0 = *(const short8*)&Vs[r * 64 + ((quad ^ (r & 7)) << 3)];
            short8 vf1 = *(const short8*)&Vs[r * 64 + (((4 + quad) ^ (r & 7)) << 3)];
            O[nt] = __builtin_amdgcn_mfma_f32_16x16x32_bf16(pf0, vf0, O[nt], 0, 0, 0);
            O[nt] = __builtin_amdgcn_mfma_f32_16x16x32_bf16(pf1, vf1, O[nt], 0, 0, 0);
        }
    }

    // epilogue
#pragma unroll
    for (int r = 0; r < 4; ++r) {
        float invl = 1.f / lrow[r];
        size_t ro = qbase + (size_t)(qt * 64 + w * 16 + quad * 4 + r) * D_MODEL;
#pragma unroll
        for (int nt = 0; nt < 4; ++nt)
            Hc[ro + nt * 16 + lx] = f2bf(O[nt][r] * invl);
    }
}

extern "C" void kernel_launch(void* const* d_in, const int* in_sizes, int n_in,
                              void* d_out, int out_size, void* d_ws, size_t ws_size,
                              hipStream_t stream) {
    const float* inQ = (const float*)d_in[0];
    const float* inK = (const float*)d_in[1];
    const float* inV = (const float*)d_in[2];
    const float* Wq  = (const float*)d_in[3];
    const float* bq  = (const float*)d_in[4];
    const float* Wk  = (const float*)d_in[5];
    const float* bk  = (const float*)d_in[6];
    const float* Wv  = (const float*)d_in[7];
    const float* bv  = (const float*)d_in[8];
    const float* Wo  = (const float*)d_in[9];
    const float* bo  = (const float*)d_in[10];
    float* out = (float*)d_out;

    const size_t NI = (size_t)MROWS * D_MODEL;      // 4M
    const size_t NW = (size_t)D_MODEL * D_MODEL;    // 1M
    ushort_t* ws  = (ushort_t*)d_ws;
    ushort_t* Qb  = ws;                // bf16 inputs
    ushort_t* Kb  = Qb  + NI;
    ushort_t* Vb  = Kb  + NI;
    ushort_t* Wqb = Vb  + NI;          // bf16 weights
    ushort_t* Wkb = Wqb + NW;
    ushort_t* Wvb = Wkb + NW;
    ushort_t* Wob = Wvb + NW;
    ushort_t* Qp  = Wob + NW;          // projections
    ushort_t* Kp  = Qp  + NI;
    ushort_t* Vtg = Kp  + NI;          // V^T [B*H][DK][SEQ]
    ushort_t* Hc  = Vtg + NI;

    // fp32 -> bf16
    cvt_bf16<<<dim3(NI / 1024, 3), 256, 0, stream>>>(
        inQ, inK, inV, inV, Qb, Kb, Vb, Vb, (int)NI);
    cvt_bf16<<<dim3(NW / 1024, 4), 256, 0, stream>>>(
        Wq, Wk, Wv, Wo, Wqb, Wkb, Wvb, Wob, (int)NW);

    // fused QKV projection (z selects), V written transposed
    GemmArgs aq{Qb, Wqb, bq, (void*)Qp, 0};
    GemmArgs ak{Kb, Wkb, bk, (void*)Kp, 0};
    GemmArgs av{Vb, Wvb, bv, (void*)Vtg, 1};
    gemm_mfma<<<dim3(MROWS / 128, D_MODEL / 128, 3), 256, 0, stream>>>(aq, ak, av);

    // attention
    flash_mfma<<<dim3(SEQ / 64, BATCH * NHEADS), 256, 0, stream>>>(Qp, Kp, Vtg, Hc);

    // output projection (fp32 out)
    GemmArgs ao{Hc, Wob, bo, (void*)out, 2};
    gemm_mfma<<<dim3(MROWS / 128, D_MODEL / 128, 1), 256, 0, stream>>>(ao, ao, ao);
}

// Round 4
// 261.790 us; speedup vs baseline: 4.9758x; 1.1230x over previous
//
#include <hip/hip_runtime.h>
#include <hip/hip_bf16.h>
#include <math.h>

#define D_MODEL 1024
#define NHEADS  16
#define DK      64
#define SEQ     2048
#define BATCH   2
#define MROWS   4096   // BATCH*SEQ

typedef unsigned short ushort_t;
using short8 = __attribute__((ext_vector_type(8))) short;
using f32x4  = __attribute__((ext_vector_type(4))) float;

__device__ __forceinline__ ushort_t f2bf(float x) {
    unsigned u = __float_as_uint(x);
    u = (u + 0x7FFFu + ((u >> 16) & 1u)) >> 16;   // RNE
    return (ushort_t)u;
}

// pack 2 floats -> 2 bf16 in one uint (v_cvt_pk_bf16_f32 on gfx950)
__device__ __forceinline__ unsigned pk2(float a, float b) {
    __hip_bfloat162 h = __float22bfloat162_rn(float2{a, b});
    unsigned u;
    __builtin_memcpy(&u, &h, 4);
    return u;
}

// async global->LDS, 16B per lane; LDS dest = wave-uniform base + lane*16
__device__ __forceinline__ void gll16(const ushort_t* g, ushort_t* l) {
    __builtin_amdgcn_global_load_lds(
        (const __attribute__((address_space(1))) void*)(g),
        (__attribute__((address_space(3))) void*)(l), 16, 0, 0);
}

// ---------------------------------------------------------------------------
// fp32 -> bf16 conversion, up to 4 tensors per launch (blockIdx.y selects)
// ---------------------------------------------------------------------------
__global__ __launch_bounds__(256) void cvt_bf16(
    const float* s0, const float* s1, const float* s2, const float* s3,
    ushort_t* d0, ushort_t* d1, ushort_t* d2, ushort_t* d3, int n)
{
    const float* s; ushort_t* d;
    switch (blockIdx.y) {
        case 0: s = s0; d = d0; break;
        case 1: s = s1; d = d1; break;
        case 2: s = s2; d = d2; break;
        default: s = s3; d = d3; break;
    }
    int i = (blockIdx.x * 256 + threadIdx.x) * 4;
    if (i < n) {
        float4 v = *(const float4*)&s[i];
        ushort4 o;
        o.x = f2bf(v.x); o.y = f2bf(v.y); o.z = f2bf(v.z); o.w = f2bf(v.w);
        *(ushort4*)&d[i] = o;
    }
}

// ---------------------------------------------------------------------------
// bf16 MFMA GEMM:  C[M,N] = (A[M,K] @ W[N,K]^T + bias) * oscale
// 128x128 tile, BK=64, 256 threads (4 waves, each 64x64), global_load_lds.
// MODE 0: bf16 row-major out (operand-swapped MFMA -> lane holds 4 consec n
//         -> b64 stores).  MODE 1: bf16 transposed out [B*H][DK][SEQ] (normal
//         orientation, 4 consec s per lane).  MODE 2: fp32 row-major out
//         (swapped -> float4 stores).
// ---------------------------------------------------------------------------
struct GemmArgs { const ushort_t* A; const ushort_t* W; const float* bias;
                  void* C; int mode; float oscale; };

template<int MODE>
__device__ __forceinline__ void gemm_core(const GemmArgs& ga,
                                          ushort_t* As, ushort_t* Bs)
{
    constexpr bool SWP = (MODE != 1);
    const int tid  = threadIdx.x;
    const int w    = tid >> 6, lane = tid & 63;
    const int quad = lane >> 4, lx = lane & 15;
    const int mw = (w >> 1) * 64, nw = (w & 1) * 64;
    const int bm = blockIdx.x * 128, bn = blockIdx.y * 128;
    const int K = D_MODEL;

    f32x4 acc[4][4];
#pragma unroll
    for (int mt = 0; mt < 4; ++mt)
#pragma unroll
        for (int nt = 0; nt < 4; ++nt)
            acc[mt][nt] = (f32x4){0.f, 0.f, 0.f, 0.f};

    float4 b4[4];
    float  bfr[4];
#pragma unroll
    for (int nt = 0; nt < 4; ++nt) {
        if (SWP) b4[nt] = *(const float4*)&ga.bias[bn + nw + nt * 16 + quad * 4];
        else     bfr[nt] = ga.bias[bn + nw + nt * 16 + lx];
    }

    for (int k0 = 0; k0 < K; k0 += 64) {
        __syncthreads();
#pragma unroll
        for (int i = 0; i < 4; ++i) {
            int r0 = (w * 4 + i) * 8;
            int rl = r0 + (lane >> 3);
            int g  = (lane & 7) ^ (rl & 7);
            gll16(&ga.A[(size_t)(bm + rl) * K + k0 + g * 8], &As[r0 * 64]);
            gll16(&ga.W[(size_t)(bn + rl) * K + k0 + g * 8], &Bs[r0 * 64]);
        }
        __syncthreads();

#pragma unroll
        for (int ks = 0; ks < 2; ++ks) {
            short8 af[4], bf[4];
#pragma unroll
            for (int mt = 0; mt < 4; ++mt) {
                int r = mw + mt * 16 + lx;
                af[mt] = *(const short8*)&As[r * 64 + (((ks * 4 + quad) ^ (r & 7)) << 3)];
            }
#pragma unroll
            for (int nt = 0; nt < 4; ++nt) {
                int r = nw + nt * 16 + lx;
                bf[nt] = *(const short8*)&Bs[r * 64 + (((ks * 4 + quad) ^ (r & 7)) << 3)];
            }
#pragma unroll
            for (int mt = 0; mt < 4; ++mt)
#pragma unroll
                for (int nt = 0; nt < 4; ++nt)
                    acc[mt][nt] = SWP
                        ? __builtin_amdgcn_mfma_f32_16x16x32_bf16(bf[nt], af[mt], acc[mt][nt], 0, 0, 0)
                        : __builtin_amdgcn_mfma_f32_16x16x32_bf16(af[mt], bf[nt], acc[mt][nt], 0, 0, 0);
        }
    }

    if (MODE == 0) {
        // swapped: lane holds C[m=lx-based][n0..n0+3] -> b64 bf16 stores
        ushort_t* C = (ushort_t*)ga.C;
        const float os = ga.oscale;
#pragma unroll
        for (int mt = 0; mt < 4; ++mt) {
            int m = bm + mw + mt * 16 + lx;
#pragma unroll
            for (int nt = 0; nt < 4; ++nt) {
                int n0 = bn + nw + nt * 16 + quad * 4;
                uint2 u;
                u.x = pk2((acc[mt][nt][0] + b4[nt].x) * os, (acc[mt][nt][1] + b4[nt].y) * os);
                u.y = pk2((acc[mt][nt][2] + b4[nt].z) * os, (acc[mt][nt][3] + b4[nt].w) * os);
                *(uint2*)&C[(size_t)m * D_MODEL + n0] = u;
            }
        }
    } else if (MODE == 2) {
        // swapped: float4 stores
        float* C = (float*)ga.C;
#pragma unroll
        for (int mt = 0; mt < 4; ++mt) {
            int m = bm + mw + mt * 16 + lx;
#pragma unroll
            for (int nt = 0; nt < 4; ++nt) {
                int n0 = bn + nw + nt * 16 + quad * 4;
                float4 v;
                v.x = acc[mt][nt][0] + b4[nt].x;
                v.y = acc[mt][nt][1] + b4[nt].y;
                v.z = acc[mt][nt][2] + b4[nt].z;
                v.w = acc[mt][nt][3] + b4[nt].w;
                *(float4*)&C[(size_t)m * D_MODEL + n0] = v;
            }
        }
    } else {
        // MODE 1, normal orientation: V^T out [(b*H+h)][d][s], 4 consec s/lane
        ushort_t* C = (ushort_t*)ga.C;
#pragma unroll
        for (int mt = 0; mt < 4; ++mt)
#pragma unroll
            for (int nt = 0; nt < 4; ++nt) {
                int n = bn + nw + nt * 16 + lx;
                int d = n & 63, h = n >> 6;
                int m0 = bm + mw + mt * 16 + quad * 4;
                int b = m0 >> 11, s0 = m0 & 2047;
                uint2 u;
                u.x = pk2(acc[mt][nt][0] + bfr[nt], acc[mt][nt][1] + bfr[nt]);
                u.y = pk2(acc[mt][nt][2] + bfr[nt], acc[mt][nt][3] + bfr[nt]);
                *(uint2*)&C[((size_t)(b * NHEADS + h) * DK + d) * SEQ + s0] = u;
            }
    }
}

__global__ __launch_bounds__(256) void gemm_mfma(GemmArgs g0, GemmArgs g1, GemmArgs g2)
{
    __shared__ ushort_t As[128 * 64];
    __shared__ ushort_t Bs[128 * 64];
    GemmArgs ga = (blockIdx.z == 0) ? g0 : ((blockIdx.z == 1) ? g1 : g2);
    if (ga.mode == 0)      gemm_core<0>(ga, As, Bs);
    else if (ga.mode == 1) gemm_core<1>(ga, As, Bs);
    else                   gemm_core<2>(ga, As, Bs);
}

// ---------------------------------------------------------------------------
// bf16 MFMA causal flash attention, transposed dataflow:
//   S^T = mfma(K-frag, Q-frag)  -> lane holds one q-row (q=lx), 16 k-cols
//   softmax: 15 in-lane ops + 2 shfls; P pack: 4 b64 LDS writes
//   O^T = mfma(V^T-frag, P-frag) -> alpha/l per-lane, b64 Hc stores
// Q pre-scaled by 1/sqrt(dk)*log2e in the projection GEMM.
// Grid (SEQ/64, BATCH*NHEADS), 256 threads = 4 waves, 16 q-rows/wave.
// ---------------------------------------------------------------------------
__global__ __launch_bounds__(256) void flash_mfma(
    const ushort_t* __restrict__ Qp, const ushort_t* __restrict__ Kp,
    const ushort_t* __restrict__ Vt, ushort_t* __restrict__ Hc)
{
    const int qt = (int)gridDim.x - 1 - (int)blockIdx.x;   // big tiles first
    const int bh = blockIdx.y;
    const int b = bh >> 4, h = bh & 15;
    const int tid  = threadIdx.x;
    const int w    = tid >> 6, lane = tid & 63;
    const int quad = lane >> 4, lx = lane & 15;

    __shared__ ushort_t Ks[64 * 64];
    __shared__ ushort_t Vs[64 * 64];      // V^T tile: row d, col k
    __shared__ ushort_t Ps[4][16 * 72];   // per-wave P[q][k], stride 72

    const size_t qbase = (size_t)(b * SEQ) * D_MODEL + h * DK;
    const size_t vbase = (size_t)bh * DK * SEQ;

    // Q fragments (row qt*64 + w*16 + lx), resident across all k-tiles
    short8 qf[2];
    {
        size_t ro = qbase + (size_t)(qt * 64 + w * 16 + lx) * D_MODEL + quad * 8;
        qf[0] = *(const short8*)&Qp[ro];
        qf[1] = *(const short8*)&Qp[ro + 32];
    }

    f32x4 O[4];           // O^T frags: d = nt*16+quad*4+r, q = lx
#pragma unroll
    for (int nt = 0; nt < 4; ++nt) O[nt] = (f32x4){0.f, 0.f, 0.f, 0.f};
    float mrow = -INFINITY, lrow = 0.f;   // per-lane state, q = lx
    const int qin = w * 16 + lx;          // q index within the 64-row tile

    for (int kt = 0; kt <= qt; ++kt) {
        __syncthreads();
#pragma unroll
        for (int i = 0; i < 2; ++i) {
            int r0 = (w + i * 4) * 8;
            int rl = r0 + (lane >> 3);
            int g  = (lane & 7) ^ (rl & 7);
            gll16(&Kp[qbase + (size_t)(kt * 64 + rl) * D_MODEL + g * 8], &Ks[r0 * 64]);
            gll16(&Vt[vbase + (size_t)rl * SEQ + kt * 64 + g * 8], &Vs[r0 * 64]);
        }
        __syncthreads();

        // S^T = K Q^T : s[nt][r] = S[q=lx][k = nt*16+quad*4+r]
        f32x4 s[4];
#pragma unroll
        for (int nt = 0; nt < 4; ++nt) {
            int r = nt * 16 + lx;
            short8 kf0 = *(const short8*)&Ks[r * 64 + ((quad ^ (r & 7)) << 3)];
            short8 kf1 = *(const short8*)&Ks[r * 64 + (((4 + quad) ^ (r & 7)) << 3)];
            f32x4 z = (f32x4){0.f, 0.f, 0.f, 0.f};
            z = __builtin_amdgcn_mfma_f32_16x16x32_bf16(kf0, qf[0], z, 0, 0, 0);
            z = __builtin_amdgcn_mfma_f32_16x16x32_bf16(kf1, qf[1], z, 0, 0, 0);
            s[nt] = z;
        }

        // causal mask (diagonal tile only); values already in log2 domain
        if (kt == qt) {
#pragma unroll
            for (int nt = 0; nt < 4; ++nt)
#pragma unroll
                for (int r = 0; r < 4; ++r)
                    if ((nt * 16 + quad * 4 + r) > qin) s[nt][r] = -INFINITY;
        }

        // online softmax: all 16 values are one q-row (q = lx)
        float tm = -INFINITY;
#pragma unroll
        for (int nt = 0; nt < 4; ++nt)
#pragma unroll
            for (int r = 0; r < 4; ++r) tm = fmaxf(tm, s[nt][r]);
        tm = fmaxf(tm, __shfl_xor(tm, 16, 64));
        tm = fmaxf(tm, __shfl_xor(tm, 32, 64));
        float mnew = fmaxf(mrow, tm);
        float alpha = __builtin_amdgcn_exp2f(mrow - mnew);
        mrow = mnew;
        float rs = 0.f;
#pragma unroll
        for (int nt = 0; nt < 4; ++nt)
#pragma unroll
            for (int r = 0; r < 4; ++r) {
                float p = __builtin_amdgcn_exp2f(s[nt][r] - mnew);
                s[nt][r] = p;
                rs += p;
            }
        rs += __shfl_xor(rs, 16, 64);
        rs += __shfl_xor(rs, 32, 64);
        lrow = lrow * alpha + rs;
#pragma unroll
        for (int nt = 0; nt < 4; ++nt)
#pragma unroll
            for (int r = 0; r < 4; ++r) O[nt][r] *= alpha;

        // P -> per-wave LDS, k-consecutive: one b64 per nt
#pragma unroll
        for (int nt = 0; nt < 4; ++nt) {
            uint2 u;
            u.x = pk2(s[nt][0], s[nt][1]);
            u.y = pk2(s[nt][2], s[nt][3]);
            *(uint2*)&Ps[w][lx * 72 + nt * 16 + quad * 4] = u;
        }

        // P A/B-frags (same-wave LDS RAW, in-order per wave)
        short8 pf0 = *(const short8*)&Ps[w][lx * 72 + quad * 8];
        short8 pf1 = *(const short8*)&Ps[w][lx * 72 + 32 + quad * 8];

        // O^T += V^T-frag x P-frag
#pragma unroll
        for (int nt = 0; nt < 4; ++nt) {
            int r = nt * 16 + lx;
            short8 vf0 = *(const short8*)&Vs[r * 64 + ((quad ^ (r & 7)) << 3)];
            short8 vf1 = *(const short8*)&Vs[r * 64 + (((4 + quad) ^ (r & 7)) << 3)];
            O[nt] = __builtin_amdgcn_mfma_f32_16x16x32_bf16(vf0, pf0, O[nt], 0, 0, 0);
            O[nt] = __builtin_amdgcn_mfma_f32_16x16x32_bf16(vf1, pf1, O[nt], 0, 0, 0);
        }
    }

    // epilogue: lane writes row q = lx, 4 consecutive d per nt (b64 stores)
    {
        float invl = 1.f / lrow;
        size_t ro = qbase + (size_t)(qt * 64 + w * 16 + lx) * D_MODEL;
#pragma unroll
        for (int nt = 0; nt < 4; ++nt) {
            uint2 u;
            u.x = pk2(O[nt][0] * invl, O[nt][1] * invl);
            u.y = pk2(O[nt][2] * invl, O[nt][3] * invl);
            *(uint2*)&Hc[ro + nt * 16 + quad * 4] = u;
        }
    }
}

extern "C" void kernel_launch(void* const* d_in, const int* in_sizes, int n_in,
                              void* d_out, int out_size, void* d_ws, size_t ws_size,
                              hipStream_t stream) {
    const float* inQ = (const float*)d_in[0];
    const float* inK = (const float*)d_in[1];
    const float* inV = (const float*)d_in[2];
    const float* Wq  = (const float*)d_in[3];
    const float* bq  = (const float*)d_in[4];
    const float* Wk  = (const float*)d_in[5];
    const float* bk  = (const float*)d_in[6];
    const float* Wv  = (const float*)d_in[7];
    const float* bv  = (const float*)d_in[8];
    const float* Wo  = (const float*)d_in[9];
    const float* bo  = (const float*)d_in[10];
    float* out = (float*)d_out;

    const size_t NI = (size_t)MROWS * D_MODEL;      // 4M
    const size_t NW = (size_t)D_MODEL * D_MODEL;    // 1M
    ushort_t* ws  = (ushort_t*)d_ws;
    ushort_t* Qb  = ws;                // bf16 inputs
    ushort_t* Kb  = Qb  + NI;
    ushort_t* Vb  = Kb  + NI;
    ushort_t* Wqb = Vb  + NI;          // bf16 weights
    ushort_t* Wkb = Wqb + NW;
    ushort_t* Wvb = Wkb + NW;
    ushort_t* Wob = Wvb + NW;
    ushort_t* Qp  = Wob + NW;          // projections
    ushort_t* Kp  = Qp  + NI;
    ushort_t* Vtg = Kp  + NI;          // V^T [B*H][DK][SEQ]
    ushort_t* Hc  = Vtg + NI;

    // fp32 -> bf16
    cvt_bf16<<<dim3(NI / 1024, 3), 256, 0, stream>>>(
        inQ, inK, inV, inV, Qb, Kb, Vb, Vb, (int)NI);
    cvt_bf16<<<dim3(NW / 1024, 4), 256, 0, stream>>>(
        Wq, Wk, Wv, Wo, Wqb, Wkb, Wvb, Wob, (int)NW);

    // fused QKV projection; Q pre-scaled by 1/sqrt(dk)*log2(e); V transposed
    const float qsc = 0.125f * 1.44269504088896340736f;
    GemmArgs aq{Qb, Wqb, bq, (void*)Qp, 0, qsc};
    GemmArgs ak{Kb, Wkb, bk, (void*)Kp, 0, 1.0f};
    GemmArgs av{Vb, Wvb, bv, (void*)Vtg, 1, 1.0f};
    gemm_mfma<<<dim3(MROWS / 128, D_MODEL / 128, 3), 256, 0, stream>>>(aq, ak, av);

    // attention
    flash_mfma<<<dim3(SEQ / 64, BATCH * NHEADS), 256, 0, stream>>>(Qp, Kp, Vtg, Hc);

    // output projection (fp32 out)
    GemmArgs ao{Hc, Wob, bo, (void*)out, 2, 1.0f};
    gemm_mfma<<<dim3(MROWS / 128, D_MODEL / 128, 1), 256, 0, stream>>>(ao, ao, ao);
}